// Round 1
// baseline (75.629 us; speedup 1.0000x reference)
//
#include <hip/hip_runtime.h>

// OsuRatingSystem: out[b] = dot(player_table[pidx[b]], map_table[midx[b]]), D=64.
// Memory-bound random gather. 16 lanes per sample: each lane loads one float4
// (16B) of the 256B row -> fully coalesced per-row segment. shfl_xor reduce
// within the 16-lane group.

__global__ __launch_bounds__(256) void osu_rating_dot_kernel(
    const int* __restrict__ pidx,
    const int* __restrict__ midx,
    const float* __restrict__ ptab,
    const float* __restrict__ mtab,
    float* __restrict__ out,
    int n)
{
    int tid = blockIdx.x * blockDim.x + threadIdx.x;
    int sample = tid >> 4;   // 16 lanes per sample
    int lane4  = tid & 15;   // which float4 of the 64-float row
    if (sample >= n) return;

    int pi = pidx[sample];
    int mi = midx[sample];

    const float4 pv = *reinterpret_cast<const float4*>(ptab + (size_t)pi * 64 + (size_t)lane4 * 4);
    const float4 mv = *reinterpret_cast<const float4*>(mtab + (size_t)mi * 64 + (size_t)lane4 * 4);

    float s = pv.x * mv.x + pv.y * mv.y + pv.z * mv.z + pv.w * mv.w;

    // Reduce across the 16 lanes of this sample's group.
    s += __shfl_xor(s, 1, 16);
    s += __shfl_xor(s, 2, 16);
    s += __shfl_xor(s, 4, 16);
    s += __shfl_xor(s, 8, 16);

    if (lane4 == 0) out[sample] = s;
}

extern "C" void kernel_launch(void* const* d_in, const int* in_sizes, int n_in,
                              void* d_out, int out_size, void* d_ws, size_t ws_size,
                              hipStream_t stream) {
    const int*   pidx = (const int*)d_in[0];
    const int*   midx = (const int*)d_in[1];
    const float* ptab = (const float*)d_in[2];
    const float* mtab = (const float*)d_in[3];
    float*       out  = (float*)d_out;

    int n = in_sizes[0];              // BATCH = 1,000,000
    int total_threads = n * 16;       // 16 lanes per sample
    int block = 256;
    int grid = (total_threads + block - 1) / block;

    osu_rating_dot_kernel<<<grid, block, 0, stream>>>(pidx, midx, ptab, mtab, out, n);
}